// Round 9
// baseline (528.885 us; speedup 1.0000x reference)
//
#include <hip/hip_runtime.h>

#define N_ 32
#define C_ 256
#define G_ 16
#define HW_ 3136          // 56*56
#define HW4_ 784          // HW/4 in vf4 units; 784 = 3*256 + 16
#define NG_ (N_ * G_)     // 512 group instances
#define EPS_ 1e-12f

typedef float vf4 __attribute__((ext_vector_type(4)));

// Integer inputs may arrive as int32 or int64; group_sizes[1]==24 in int32
// layout, ==0 (high word of gs[0]) in int64 LE layout. Values < 2^31 so the
// low word is the value in int64 mode.
__device__ __forceinline__ int rd_int(const int* __restrict__ p, int i, bool is64) {
    return is64 ? p[2 * i] : p[i];
}

__device__ __forceinline__ void acc4(const vf4 v, float& s, float& s2) {
    s += v.x + v.y + v.z + v.w;
    s2 = fmaf(v.x, v.x, s2);
    s2 = fmaf(v.y, v.y, s2);
    s2 = fmaf(v.z, v.z, s2);
    s2 = fmaf(v.w, v.w, s2);
}

__device__ __forceinline__ vf4 aff(const vf4 v, float sc, float sh) {
    vf4 r;
    r.x = fmaf(v.x, sc, sh);
    r.y = fmaf(v.y, sc, sh);
    r.z = fmaf(v.z, sc, sh);
    r.w = fmaf(v.w, sc, sh);
    return r;
}

// Last-arriver publishes the group's stats (device-scope atomics throughout:
// per-XCD L2s are not cross-coherent, plain loads/stores could be stale).
__device__ __forceinline__ void vgn_release(
    float* __restrict__ gS, float* __restrict__ gS2,
    float* __restrict__ gMu, float* __restrict__ gIv,
    int* __restrict__ gFlag, int gi, int gsz)
{
    const float S = atomicAdd(&gS[gi],  0.0f);   // coherent read
    const float Q = atomicAdd(&gS2[gi], 0.0f);
    const float cnt = (float)gsz * (float)HW_;
    const float mu  = S / cnt;
    const float var = (Q - mu * S) / (cnt - 1.0f);   // ddof=1, matches ref
    const float iv  = rsqrtf(var + EPS_);
    atomicExch(&gMu[gi], mu);
    atomicExch(&gIv[gi], iv);
    __threadfence();                                  // stats before flag
    atomicExch(&gFlag[gi], 1);
}

// ---------------------------------------------------------------------------
// v8: ONE kernel, ONE read of x, ONE write of out. 4096 blocks x 256 thr
// (8 blk/CU, 32 waves/CU); block b owns permuted positions {2m, 2m+1} of
// image n (b = n*128 + m). A group instance (n,g) therefore spans <= 16
// CONSECUTIVE blocks. Instead of a kernel boundary between stats and
// normalize, a per-group atomic protocol: accumulate (S,S2) -> fence ->
// count; gsz-th arriver computes mu/ivar and sets the flag; spinners sleep.
// Phase-1 never waits, so every dispatched block contributes before any
// spin; waiters depend only on blocks <= 15 dispatch-indices away (resident
// window 2048 >> 16) -> progress guaranteed. The x data stays in REGISTERS
// across the sync (24 VGPRs), so there is no second read pass at all.
// Exonerated by R1-R7 (all ~73 us): store type, occupancy, load batching,
// gather order, prologue. This attacks the only untouched structure: the
// multi-dispatch pipeline itself (2 seams + extra read pass + 3 ramps).
// (Resubmission — R8 bench was lost to a GPU acquisition timeout.)
// ---------------------------------------------------------------------------
__global__ __launch_bounds__(256, 8) void vgn_onepass(
    const float* __restrict__ x,
    const int*   __restrict__ indexes,
    const int*   __restrict__ group_sizes,
    const float* __restrict__ weight,
    const float* __restrict__ bias,
    float* __restrict__ gS,   float* __restrict__ gS2,
    float* __restrict__ gMu,  float* __restrict__ gIv,
    int*   __restrict__ gCnt, int*   __restrict__ gFlag,
    float* __restrict__ out)
{
    const bool is64 = (group_sizes[1] == 0);
    const int t  = threadIdx.x;
    const int n  = blockIdx.x >> 7;            // 128 blocks per image
    const int p0 = (blockIdx.x & 127) * 2;     // permuted positions (=channels)

    const int src0 = rd_int(indexes, n * C_ + p0,     is64);
    const int src1 = rd_int(indexes, n * C_ + p0 + 1, is64);
    const vf4* q0 = (const vf4*)x + (size_t)src0 * HW4_;
    const vf4* q1 = (const vf4*)x + (size_t)src1 * HW4_;

    // ---- phase 1: load both rows into registers, per-row S / S2
    vf4 a0 = q0[t], b0 = q0[t + 256], c0 = q0[t + 512];
    vf4 a1 = q1[t], b1 = q1[t + 256], c1 = q1[t + 512];

    float sA = 0.f, qA = 0.f, sB = 0.f, qB = 0.f;
    if (t < 16) {                              // 784 = 3*256 + 16 tail
        vf4 d0 = q0[768 + t];
        vf4 d1 = q1[768 + t];
        acc4(d0, sA, qA);
        acc4(d1, sB, qB);
    }
    acc4(a0, sA, qA); acc4(b0, sA, qA); acc4(c0, sA, qA);
    acc4(a1, sB, qB); acc4(b1, sB, qB); acc4(c1, sB, qB);

    #pragma unroll
    for (int off = 32; off > 0; off >>= 1) {
        sA += __shfl_down(sA, off);
        qA += __shfl_down(qA, off);
        sB += __shfl_down(sB, off);
        qB += __shfl_down(qB, off);
    }

    __shared__ float red[4][4];                // [wave][val]
    __shared__ float sSc[2], sSh[2];
    if ((t & 63) == 0) {
        const int w = t >> 6;
        red[w][0] = sA; red[w][1] = qA; red[w][2] = sB; red[w][3] = qB;
    }
    __syncthreads();

    // ---- group protocol (thread 0 only; others park at the barrier)
    if (t == 0) {
        const float S0 = red[0][0] + red[1][0] + red[2][0] + red[3][0];
        const float Q0 = red[0][1] + red[1][1] + red[2][1] + red[3][1];
        const float S1 = red[0][2] + red[1][2] + red[2][2] + red[3][2];
        const float Q1 = red[0][3] + red[1][3] + red[2][3] + red[3][3];

        int g0 = 0, g1 = 0, P = 0;
        #pragma unroll
        for (int k = 0; k < G_; k++) {
            P += rd_int(group_sizes, k, is64);
            if (p0     >= P) g0++;
            if (p0 + 1 >= P) g1++;
        }
        const int gsz0 = rd_int(group_sizes, g0, is64);
        const int gsz1 = rd_int(group_sizes, g1, is64);
        const int gi0 = n * G_ + g0;
        const int gi1 = n * G_ + g1;

        // contribute row 0, then row 1 (adds fenced before the count inc)
        atomicAdd(&gS[gi0], S0);
        atomicAdd(&gS2[gi0], Q0);
        __threadfence();
        if (atomicAdd(&gCnt[gi0], 1) == gsz0 - 1)
            vgn_release(gS, gS2, gMu, gIv, gFlag, gi0, gsz0);

        atomicAdd(&gS[gi1], S1);
        atomicAdd(&gS2[gi1], Q1);
        __threadfence();
        if (atomicAdd(&gCnt[gi1], 1) == gsz1 - 1)
            vgn_release(gS, gS2, gMu, gIv, gFlag, gi1, gsz1);

        // wait for stats (dependency span <= 15 neighboring blocks)
        while (atomicAdd(&gFlag[gi0], 0) == 0) __builtin_amdgcn_s_sleep(2);
        const float mu0 = atomicAdd(&gMu[gi0], 0.0f);
        const float iv0 = atomicAdd(&gIv[gi0], 0.0f);
        float mu1, iv1;
        if (gi1 == gi0) { mu1 = mu0; iv1 = iv0; }
        else {
            while (atomicAdd(&gFlag[gi1], 0) == 0) __builtin_amdgcn_s_sleep(2);
            mu1 = atomicAdd(&gMu[gi1], 0.0f);
            iv1 = atomicAdd(&gIv[gi1], 0.0f);
        }

        const float sc0 = iv0 * weight[p0];
        const float sc1 = iv1 * weight[p0 + 1];
        sSc[0] = sc0; sSh[0] = fmaf(-mu0, sc0, bias[p0]);
        sSc[1] = sc1; sSh[1] = fmaf(-mu1, sc1, bias[p0 + 1]);
    }
    __syncthreads();

    // ---- phase 2: pure write from registers (no second read pass); target
    // is the SAME flat row (reverse permutation is the inverse of the gather)
    const float sc0 = sSc[0], sh0 = sSh[0];
    const float sc1 = sSc[1], sh1 = sSh[1];
    vf4* o0 = (vf4*)out + (size_t)src0 * HW4_;
    vf4* o1 = (vf4*)out + (size_t)src1 * HW4_;

    o0[t]       = aff(a0, sc0, sh0);
    o0[t + 256] = aff(b0, sc0, sh0);
    o0[t + 512] = aff(c0, sc0, sh0);
    o1[t]       = aff(a1, sc1, sh1);
    o1[t + 256] = aff(b1, sc1, sh1);
    o1[t + 512] = aff(c1, sc1, sh1);
    if (t < 16) {                              // tails re-read (L1/L2-hot)
        o0[768 + t] = aff(q0[768 + t], sc0, sh0);
        o1[768 + t] = aff(q1[768 + t], sc1, sh1);
    }
}

// ---------------------------------------------------------------------------
extern "C" void kernel_launch(void* const* d_in, const int* in_sizes, int n_in,
                              void* d_out, int out_size, void* d_ws, size_t ws_size,
                              hipStream_t stream) {
    const float* x           = (const float*)d_in[0];
    const float* weight      = (const float*)d_in[1];
    const float* bias        = (const float*)d_in[2];
    const int*   group_sizes = (const int*)  d_in[3];
    const int*   indexes     = (const int*)  d_in[4];
    // d_in[5] = reverse_indexes (unused: scatter target == gather source)

    float* gS    = (float*)d_ws;               // 6 x 512 x 4 B = 12 KB total
    float* gS2   = gS  + NG_;
    float* gMu   = gS2 + NG_;
    float* gIv   = gMu + NG_;
    int*   gCnt  = (int*)(gIv + NG_);
    int*   gFlag = gCnt + NG_;

    // protocol state must be zero each replay (workspace is re-poisoned)
    hipMemsetAsync(d_ws, 0, 6 * NG_ * sizeof(float), stream);

    vgn_onepass<<<dim3(N_ * C_ / 2), dim3(256), 0, stream>>>(
        x, indexes, group_sizes, weight, bias,
        gS, gS2, gMu, gIv, gCnt, gFlag, (float*)d_out);
}

// Round 12
// 204.697 us; speedup vs baseline: 2.5837x; 2.5837x over previous
//
#include <hip/hip_runtime.h>

#define N_ 32
#define C_ 256
#define G_ 16
#define HW_ 3136          // 56*56
#define HW4_ 784          // HW/4 in vf4 units
#define RPB_ 4            // rows per block
#define SPAN_ (RPB_ * HW4_)   // 3136 vf4 per block, contiguous
#define EPS_ 1e-12f

typedef float vf4 __attribute__((ext_vector_type(4)));
typedef float vf2 __attribute__((ext_vector_type(2)));

// Integer inputs may arrive as int32 or int64; group_sizes[1]==24 in int32
// layout, ==0 (high word of gs[0]) in int64 LE layout. Values < 2^31 so the
// low word is the value in int64 mode.
__device__ __forceinline__ int rd_int(const int* __restrict__ p, int i, bool is64) {
    return is64 ? p[2 * i] : p[i];
}

__device__ __forceinline__ void acc4(const vf4 v, float& s, float& s2) {
    s += v.x + v.y + v.z + v.w;
    s2 = fmaf(v.x, v.x, s2);
    s2 = fmaf(v.y, v.y, s2);
    s2 = fmaf(v.z, v.z, s2);
    s2 = fmaf(v.w, v.w, s2);
}

__device__ __forceinline__ vf4 aff(const vf4 v, float sc, float sh) {
    vf4 r;
    r.x = fmaf(v.x, sc, sh);
    r.y = fmaf(v.y, sc, sh);
    r.z = fmaf(v.z, sc, sh);
    r.w = fmaf(v.w, sc, sh);
    return r;
}

// ---------------------------------------------------------------------------
// v9: attack read-side MLP. Ledger: store type (R6), gather order + prologue
// (R7), occupancy, seams -- all null at ~73 us kernel-sum; sync-in-kernel
// (v5 coop 286 us, v8 atomics 435 us) strongly negative. Remaining suspect:
// loads-in-flight per wave. Evidence: 16 waves/CU x ~8 inflight = 2.38 TB/s
// (v2); 32 waves/CU x 6 = ~2.9 TB/s (v4/v6/v7) -- scales with the product.
// Reads are latency-bound (writes aren't: harness fill = 6.8 TB/s).
//
// v9 = v7 skeleton (natural-order bulk streams + tiny permuted-stats kernel)
// with 4 rows/block: each block reads a CONTIGUOUS 3136-vf4 span; each
// thread issues 12 (+1 tail) vf4 loads before any consumption. Row identity
// of each load is compile-time (boundaries at loads 3/6/9, 16-lane-aligned
// selects). 2048 blocks x 256 thr, launch_bounds(256,8) -> 32 waves/CU.
// Target: ~2x outstanding reads/CU vs v7 at unchanged occupancy.
// (Second resubmission — R10 and R11 benches both lost to GPU acquisition
// timeouts; kernel unchanged so the eventual measurement tests this change.)
// ---------------------------------------------------------------------------

// Kernel 1: 4 natural rows per block: S / S2 per row -> rsums[row*2+{0,1}]
__global__ __launch_bounds__(256, 8) void vgn_reduce(
    const float* __restrict__ x,
    float*       __restrict__ rsums)
{
    const int t = threadIdx.x;
    const vf4* p = (const vf4*)x + (size_t)blockIdx.x * SPAN_;

    // 12 full loads + 64-lane tail, all issued before any consumption
    vf4 v0 = p[t],          v1 = p[t + 256],  v2  = p[t + 512];
    vf4 v3 = p[t + 768],    v4 = p[t + 1024], v5  = p[t + 1280];
    vf4 v6 = p[t + 1536],   v7 = p[t + 1792], v8  = p[t + 2048];
    vf4 v9 = p[t + 2304],   v10 = p[t + 2560], v11 = p[t + 2816];
    vf4 vt;
    if (t < 64) vt = p[3072 + t];

    // element e = i*256 + t; row = e / 784. Boundaries: 784, 1568, 2352.
    float s0 = 0.f, q0 = 0.f, s1 = 0.f, q1 = 0.f;
    float s2 = 0.f, q2 = 0.f, s3 = 0.f, q3 = 0.f;
    acc4(v0, s0, q0); acc4(v1, s0, q0); acc4(v2, s0, q0);
    if (t < 16) acc4(v3, s0, q0); else acc4(v3, s1, q1);
    acc4(v4, s1, q1); acc4(v5, s1, q1);
    if (t < 32) acc4(v6, s1, q1); else acc4(v6, s2, q2);
    acc4(v7, s2, q2); acc4(v8, s2, q2);
    if (t < 48) acc4(v9, s2, q2); else acc4(v9, s3, q3);
    acc4(v10, s3, q3); acc4(v11, s3, q3);
    if (t < 64) acc4(vt, s3, q3);

    #pragma unroll
    for (int off = 32; off > 0; off >>= 1) {
        s0 += __shfl_down(s0, off); q0 += __shfl_down(q0, off);
        s1 += __shfl_down(s1, off); q1 += __shfl_down(q1, off);
        s2 += __shfl_down(s2, off); q2 += __shfl_down(q2, off);
        s3 += __shfl_down(s3, off); q3 += __shfl_down(q3, off);
    }

    __shared__ float red[4][8];            // [wave][s0 q0 s1 q1 s2 q2 s3 q3]
    if ((t & 63) == 0) {
        const int w = t >> 6;
        red[w][0] = s0; red[w][1] = q0; red[w][2] = s1; red[w][3] = q1;
        red[w][4] = s2; red[w][5] = q2; red[w][6] = s3; red[w][7] = q3;
    }
    __syncthreads();
    if (t < 8)                             // rsums[(blk*4 + t/2)*2 + t%2]
        rsums[blockIdx.x * 8 + t] =
            red[0][t] + red[1][t] + red[2][t] + red[3][t];
}

// Middle kernel (unchanged from v7): one 64-thread block per (n, group).
// Gathers per-row partials through indexes (cache-resident), computes
// mu/ivar, scatters per-row scale/shift INDEXED BY SOURCE ROW.
__global__ __launch_bounds__(64) void vgn_stats(
    const int*   __restrict__ indexes,
    const int*   __restrict__ group_sizes,
    const float* __restrict__ weight,
    const float* __restrict__ bias,
    const float* __restrict__ rsums,
    float*       __restrict__ scaleS,
    float*       __restrict__ shiftS)
{
    const bool is64 = (group_sizes[1] == 0);
    const int n = blockIdx.x >> 4;         // G_ == 16
    const int g = blockIdx.x & (G_ - 1);
    const int l = threadIdx.x;             // 0..63

    int Pg = 0;
    for (int k = 0; k < g; k++) Pg += rd_int(group_sizes, k, is64);
    const int gsz = rd_int(group_sizes, g, is64);

    int src = 0;
    float a = 0.f, b = 0.f;
    if (l < gsz) {
        src = rd_int(indexes, n * C_ + Pg + l, is64);   // global source row
        const vf2 pr = ((const vf2*)rsums)[src];
        a = pr.x; b = pr.y;
    }
    float A = a, B = b;
    #pragma unroll
    for (int off = 32; off > 0; off >>= 1) {
        A += __shfl_down(A, off);
        B += __shfl_down(B, off);
    }
    A = __shfl(A, 0);
    B = __shfl(B, 0);

    if (l < gsz) {
        const float cnt = (float)gsz * (float)HW_;
        const float mu  = A / cnt;
        const float var = (B - mu * A) / (cnt - 1.0f);  // ddof=1, matches ref
        const float ivr = rsqrtf(var + EPS_);
        const int   c   = Pg + l;                       // channel of this row
        const float sc  = ivr * weight[c];
        scaleS[src] = sc;
        shiftS[src] = fmaf(-mu, sc, bias[c]);
    }
}

// Kernel 2: 4 natural rows per block, pure stream. Per-row scale/shift are
// block-uniform scalar (SGPR) loads; same compile-time row mapping.
__global__ __launch_bounds__(256, 8) void vgn_norm(
    const float* __restrict__ x,
    const float* __restrict__ scaleS,
    const float* __restrict__ shiftS,
    float*       __restrict__ out)
{
    const int t = threadIdx.x;
    const size_t base = (size_t)blockIdx.x * SPAN_;
    const vf4* p = (const vf4*)x + base;
    vf4*       o = (vf4*)out     + base;
    const int  r0 = blockIdx.x * RPB_;

    // issue all streaming loads first
    vf4 v0 = p[t],          v1 = p[t + 256],  v2  = p[t + 512];
    vf4 v3 = p[t + 768],    v4 = p[t + 1024], v5  = p[t + 1280];
    vf4 v6 = p[t + 1536],   v7 = p[t + 1792], v8  = p[t + 2048];
    vf4 v9 = p[t + 2304],   v10 = p[t + 2560], v11 = p[t + 2816];
    vf4 vt;
    if (t < 64) vt = p[3072 + t];

    // block-uniform -> scalar loads, ride under the vector loads
    const float sc0 = scaleS[r0],     sh0 = shiftS[r0];
    const float sc1 = scaleS[r0 + 1], sh1 = shiftS[r0 + 1];
    const float sc2 = scaleS[r0 + 2], sh2 = shiftS[r0 + 2];
    const float sc3 = scaleS[r0 + 3], sh3 = shiftS[r0 + 3];

    o[t]        = aff(v0, sc0, sh0);
    o[t + 256]  = aff(v1, sc0, sh0);
    o[t + 512]  = aff(v2, sc0, sh0);
    o[t + 768]  = (t < 16) ? aff(v3, sc0, sh0) : aff(v3, sc1, sh1);
    o[t + 1024] = aff(v4, sc1, sh1);
    o[t + 1280] = aff(v5, sc1, sh1);
    o[t + 1536] = (t < 32) ? aff(v6, sc1, sh1) : aff(v6, sc2, sh2);
    o[t + 1792] = aff(v7, sc2, sh2);
    o[t + 2048] = aff(v8, sc2, sh2);
    o[t + 2304] = (t < 48) ? aff(v9, sc2, sh2) : aff(v9, sc3, sh3);
    o[t + 2560] = aff(v10, sc3, sh3);
    o[t + 2816] = aff(v11, sc3, sh3);
    if (t < 64)
        o[3072 + t] = aff(vt, sc3, sh3);
}

// ---------------------------------------------------------------------------
extern "C" void kernel_launch(void* const* d_in, const int* in_sizes, int n_in,
                              void* d_out, int out_size, void* d_ws, size_t ws_size,
                              hipStream_t stream) {
    const float* x           = (const float*)d_in[0];
    const float* weight      = (const float*)d_in[1];
    const float* bias        = (const float*)d_in[2];
    const int*   group_sizes = (const int*)  d_in[3];
    const int*   indexes     = (const int*)  d_in[4];
    // d_in[5] = reverse_indexes (unused: permutation handled via indexes on
    // the tiny rsums array; bulk kernels are permutation-free)

    float* rsums  = (float*)d_ws;                    // 8192 vf2  = 64 KB
    float* scaleS = (float*)d_ws + 2 * N_ * C_;      // 8192 f32  = 32 KB
    float* shiftS = scaleS + N_ * C_;                // 8192 f32  = 32 KB
    float* outp   = (float*)d_out;

    dim3 blkBulk(256), gridBulk(N_ * C_ / RPB_);     // 2048 blocks
    vgn_reduce<<<gridBulk, blkBulk, 0, stream>>>(x, rsums);
    vgn_stats <<<dim3(N_ * G_), dim3(64), 0, stream>>>(indexes, group_sizes,
                                                       weight, bias, rsums,
                                                       scaleS, shiftS);
    vgn_norm  <<<gridBulk, blkBulk, 0, stream>>>(x, scaleS, shiftS, outp);
}

// Round 15
// 201.524 us; speedup vs baseline: 2.6244x; 1.0157x over previous
//
#include <hip/hip_runtime.h>

#define N_ 32
#define C_ 256
#define G_ 16
#define HW_ 3136          // 56*56
#define HW4_ 784          // HW/4 in vf4 units
#define RPB_ 4            // rows per block
#define SPAN_ (RPB_ * HW4_)   // 3136 vf4 per block, contiguous
#define EPS_ 1e-12f

typedef float vf4 __attribute__((ext_vector_type(4)));
typedef float vf2 __attribute__((ext_vector_type(2)));

// Integer inputs may arrive as int32 or int64; group_sizes[1]==24 in int32
// layout, ==0 (high word of gs[0]) in int64 LE layout. Values < 2^31 so the
// low word is the value in int64 mode.
__device__ __forceinline__ int rd_int(const int* __restrict__ p, int i, bool is64) {
    return is64 ? p[2 * i] : p[i];
}

__device__ __forceinline__ void acc4(const vf4 v, float& s, float& s2) {
    s += v.x + v.y + v.z + v.w;
    s2 = fmaf(v.x, v.x, s2);
    s2 = fmaf(v.y, v.y, s2);
    s2 = fmaf(v.z, v.z, s2);
    s2 = fmaf(v.w, v.w, s2);
}

__device__ __forceinline__ vf4 aff(const vf4 v, float sc, float sh) {
    vf4 r;
    r.x = fmaf(v.x, sc, sh);
    r.y = fmaf(v.y, sc, sh);
    r.z = fmaf(v.z, sc, sh);
    r.w = fmaf(v.w, sc, sh);
    return r;
}

// ---------------------------------------------------------------------------
// v10 = v9 with ONE change: __builtin_nontemporal_load on both bulk x reads.
// (Third submission — R13 and R14 benches both lost to GPU acquisition
// timeouts; kernel unchanged so the eventual measurement tests this change.)
//
// Ledger: store type (R6), gather order + prologue (R7), occupancy, seams,
// read-side MLP (R12: v9 null at ~390 KB in-flight/CU) -- all exonerated at
// ~73 us kernel-sum. Model that fits all data: pure-read streams cap at
// ~3 TB/s while pure-write hits 6.8 (harness fill) and copy 6.3 total.
// Remaining mechanism: READ-MISS CACHE ALLOCATION halves read streams; the
// fill's own tiny FETCH (14.5 KB) + v8's FETCH=51 MB suggest it uses
// no-allocate NT stores to reach 6.8. gfx950 loads expose nt/sc bits via
// __builtin_nontemporal_load -- apply to k1 and k2 x-streams (k2's L3 hit is
// forfeited once k1 reads NT, so NT-both is the clean single variable;
// worst case flat, not regression).
// Predict: NT works -> kernel-sum ~55, e2e ~185. Flat -> read ceiling is
// structural; declare roofline next round with the full evidence chain.
// ---------------------------------------------------------------------------

// Kernel 1: 4 natural rows per block: S / S2 per row -> rsums[row*2+{0,1}]
__global__ __launch_bounds__(256, 8) void vgn_reduce(
    const float* __restrict__ x,
    float*       __restrict__ rsums)
{
    const int t = threadIdx.x;
    const vf4* p = (const vf4*)x + (size_t)blockIdx.x * SPAN_;

    // 12 full loads + 64-lane tail, all issued before any consumption (NT)
    vf4 v0 = __builtin_nontemporal_load(p + t);
    vf4 v1 = __builtin_nontemporal_load(p + t + 256);
    vf4 v2 = __builtin_nontemporal_load(p + t + 512);
    vf4 v3 = __builtin_nontemporal_load(p + t + 768);
    vf4 v4 = __builtin_nontemporal_load(p + t + 1024);
    vf4 v5 = __builtin_nontemporal_load(p + t + 1280);
    vf4 v6 = __builtin_nontemporal_load(p + t + 1536);
    vf4 v7 = __builtin_nontemporal_load(p + t + 1792);
    vf4 v8 = __builtin_nontemporal_load(p + t + 2048);
    vf4 v9 = __builtin_nontemporal_load(p + t + 2304);
    vf4 v10 = __builtin_nontemporal_load(p + t + 2560);
    vf4 v11 = __builtin_nontemporal_load(p + t + 2816);
    vf4 vt;
    if (t < 64) vt = __builtin_nontemporal_load(p + 3072 + t);

    // element e = i*256 + t; row = e / 784. Boundaries: 784, 1568, 2352.
    float s0 = 0.f, q0 = 0.f, s1 = 0.f, q1 = 0.f;
    float s2 = 0.f, q2 = 0.f, s3 = 0.f, q3 = 0.f;
    acc4(v0, s0, q0); acc4(v1, s0, q0); acc4(v2, s0, q0);
    if (t < 16) acc4(v3, s0, q0); else acc4(v3, s1, q1);
    acc4(v4, s1, q1); acc4(v5, s1, q1);
    if (t < 32) acc4(v6, s1, q1); else acc4(v6, s2, q2);
    acc4(v7, s2, q2); acc4(v8, s2, q2);
    if (t < 48) acc4(v9, s2, q2); else acc4(v9, s3, q3);
    acc4(v10, s3, q3); acc4(v11, s3, q3);
    if (t < 64) acc4(vt, s3, q3);

    #pragma unroll
    for (int off = 32; off > 0; off >>= 1) {
        s0 += __shfl_down(s0, off); q0 += __shfl_down(q0, off);
        s1 += __shfl_down(s1, off); q1 += __shfl_down(q1, off);
        s2 += __shfl_down(s2, off); q2 += __shfl_down(q2, off);
        s3 += __shfl_down(s3, off); q3 += __shfl_down(q3, off);
    }

    __shared__ float red[4][8];            // [wave][s0 q0 s1 q1 s2 q2 s3 q3]
    if ((t & 63) == 0) {
        const int w = t >> 6;
        red[w][0] = s0; red[w][1] = q0; red[w][2] = s1; red[w][3] = q1;
        red[w][4] = s2; red[w][5] = q2; red[w][6] = s3; red[w][7] = q3;
    }
    __syncthreads();
    if (t < 8)                             // rsums[(blk*4 + t/2)*2 + t%2]
        rsums[blockIdx.x * 8 + t] =
            red[0][t] + red[1][t] + red[2][t] + red[3][t];
}

// Middle kernel (unchanged): one 64-thread block per (n, group). Gathers
// per-row partials through indexes (cache-resident), computes mu/ivar,
// scatters per-row scale/shift INDEXED BY SOURCE ROW.
__global__ __launch_bounds__(64) void vgn_stats(
    const int*   __restrict__ indexes,
    const int*   __restrict__ group_sizes,
    const float* __restrict__ weight,
    const float* __restrict__ bias,
    const float* __restrict__ rsums,
    float*       __restrict__ scaleS,
    float*       __restrict__ shiftS)
{
    const bool is64 = (group_sizes[1] == 0);
    const int n = blockIdx.x >> 4;         // G_ == 16
    const int g = blockIdx.x & (G_ - 1);
    const int l = threadIdx.x;             // 0..63

    int Pg = 0;
    for (int k = 0; k < g; k++) Pg += rd_int(group_sizes, k, is64);
    const int gsz = rd_int(group_sizes, g, is64);

    int src = 0;
    float a = 0.f, b = 0.f;
    if (l < gsz) {
        src = rd_int(indexes, n * C_ + Pg + l, is64);   // global source row
        const vf2 pr = ((const vf2*)rsums)[src];
        a = pr.x; b = pr.y;
    }
    float A = a, B = b;
    #pragma unroll
    for (int off = 32; off > 0; off >>= 1) {
        A += __shfl_down(A, off);
        B += __shfl_down(B, off);
    }
    A = __shfl(A, 0);
    B = __shfl(B, 0);

    if (l < gsz) {
        const float cnt = (float)gsz * (float)HW_;
        const float mu  = A / cnt;
        const float var = (B - mu * A) / (cnt - 1.0f);  // ddof=1, matches ref
        const float ivr = rsqrtf(var + EPS_);
        const int   c   = Pg + l;                       // channel of this row
        const float sc  = ivr * weight[c];
        scaleS[src] = sc;
        shiftS[src] = fmaf(-mu, sc, bias[c]);
    }
}

// Kernel 2: 4 natural rows per block, pure stream (NT reads, plain stores).
// Per-row scale/shift are block-uniform scalar (SGPR) loads.
__global__ __launch_bounds__(256, 8) void vgn_norm(
    const float* __restrict__ x,
    const float* __restrict__ scaleS,
    const float* __restrict__ shiftS,
    float*       __restrict__ out)
{
    const int t = threadIdx.x;
    const size_t base = (size_t)blockIdx.x * SPAN_;
    const vf4* p = (const vf4*)x + base;
    vf4*       o = (vf4*)out     + base;
    const int  r0 = blockIdx.x * RPB_;

    // issue all streaming loads first (NT: x is not re-read after this)
    vf4 v0 = __builtin_nontemporal_load(p + t);
    vf4 v1 = __builtin_nontemporal_load(p + t + 256);
    vf4 v2 = __builtin_nontemporal_load(p + t + 512);
    vf4 v3 = __builtin_nontemporal_load(p + t + 768);
    vf4 v4 = __builtin_nontemporal_load(p + t + 1024);
    vf4 v5 = __builtin_nontemporal_load(p + t + 1280);
    vf4 v6 = __builtin_nontemporal_load(p + t + 1536);
    vf4 v7 = __builtin_nontemporal_load(p + t + 1792);
    vf4 v8 = __builtin_nontemporal_load(p + t + 2048);
    vf4 v9 = __builtin_nontemporal_load(p + t + 2304);
    vf4 v10 = __builtin_nontemporal_load(p + t + 2560);
    vf4 v11 = __builtin_nontemporal_load(p + t + 2816);
    vf4 vt;
    if (t < 64) vt = __builtin_nontemporal_load(p + 3072 + t);

    // block-uniform -> scalar loads, ride under the vector loads
    const float sc0 = scaleS[r0],     sh0 = shiftS[r0];
    const float sc1 = scaleS[r0 + 1], sh1 = shiftS[r0 + 1];
    const float sc2 = scaleS[r0 + 2], sh2 = shiftS[r0 + 2];
    const float sc3 = scaleS[r0 + 3], sh3 = shiftS[r0 + 3];

    o[t]        = aff(v0, sc0, sh0);
    o[t + 256]  = aff(v1, sc0, sh0);
    o[t + 512]  = aff(v2, sc0, sh0);
    o[t + 768]  = (t < 16) ? aff(v3, sc0, sh0) : aff(v3, sc1, sh1);
    o[t + 1024] = aff(v4, sc1, sh1);
    o[t + 1280] = aff(v5, sc1, sh1);
    o[t + 1536] = (t < 32) ? aff(v6, sc1, sh1) : aff(v6, sc2, sh2);
    o[t + 1792] = aff(v7, sc2, sh2);
    o[t + 2048] = aff(v8, sc2, sh2);
    o[t + 2304] = (t < 48) ? aff(v9, sc2, sh2) : aff(v9, sc3, sh3);
    o[t + 2560] = aff(v10, sc3, sh3);
    o[t + 2816] = aff(v11, sc3, sh3);
    if (t < 64)
        o[3072 + t] = aff(vt, sc3, sh3);
}

// ---------------------------------------------------------------------------
extern "C" void kernel_launch(void* const* d_in, const int* in_sizes, int n_in,
                              void* d_out, int out_size, void* d_ws, size_t ws_size,
                              hipStream_t stream) {
    const float* x           = (const float*)d_in[0];
    const float* weight      = (const float*)d_in[1];
    const float* bias        = (const float*)d_in[2];
    const int*   group_sizes = (const int*)  d_in[3];
    const int*   indexes     = (const int*)  d_in[4];
    // d_in[5] = reverse_indexes (unused: permutation handled via indexes on
    // the tiny rsums array; bulk kernels are permutation-free)

    float* rsums  = (float*)d_ws;                    // 8192 vf2  = 64 KB
    float* scaleS = (float*)d_ws + 2 * N_ * C_;      // 8192 f32  = 32 KB
    float* shiftS = scaleS + N_ * C_;                // 8192 f32  = 32 KB
    float* outp   = (float*)d_out;

    dim3 blkBulk(256), gridBulk(N_ * C_ / RPB_);     // 2048 blocks
    vgn_reduce<<<gridBulk, blkBulk, 0, stream>>>(x, rsums);
    vgn_stats <<<dim3(N_ * G_), dim3(64), 0, stream>>>(indexes, group_sizes,
                                                       weight, bias, rsums,
                                                       scaleS, shiftS);
    vgn_norm  <<<gridBulk, blkBulk, 0, stream>>>(x, scaleS, shiftS, outp);
}